// Round 10
// baseline (334.046 us; speedup 1.0000x reference)
//
#include <hip/hip_runtime.h>

#define NPTS 65552          // 16 * (64*64 + 1)
#define MPAD 65664          // 513 * 128
#define NVOX 274625         // 65^3

typedef unsigned short u16;
typedef __attribute__((ext_vector_type(8))) short bf16x8;
typedef __attribute__((ext_vector_type(4))) float f32x4;
typedef __attribute__((ext_vector_type(4))) unsigned short us4;

__device__ __forceinline__ u16 f2bf(float f) {
  unsigned int u = __float_as_uint(f);
  return (u16)((u + 0x7FFFu + ((u >> 16) & 1u)) >> 16);
}

// ---------------- coords from depth ----------------
__global__ void coords_kernel(const float* __restrict__ depth, int* __restrict__ pcoord) {
  int b = blockIdx.x, tid = threadIdx.x;
  const float* d = depth + b * 4096;
  float mn = 1e30f, mx = -1e30f;
  for (int p = tid; p < 4096; p += 256) {
    float v = d[p];
    mn = fminf(mn, v);
    mx = fmaxf(mx, v);
  }
  __shared__ float smn[256], smx[256];
  smn[tid] = mn; smx[tid] = mx;
  __syncthreads();
  for (int s = 128; s > 0; s >>= 1) {
    if (tid < s) {
      smn[tid] = fminf(smn[tid], smn[tid + s]);
      smx[tid] = fmaxf(smx[tid], smx[tid + s]);
    }
    __syncthreads();
  }
  mn = smn[0]; mx = smx[0];
  float den = mx - mn + 1e-8f;
  for (int p = tid; p < 4096; p += 256) {
    int i = p >> 6, j = p & 63;
    float x = (float)j / 63.0f;       // matches jnp arange/63 (IEEE div)
    float y = (float)i / 63.0f;
    float z = (d[p] - mn) / den;
    int cx = (int)rintf(x * 64.0f);   // *64 exact, rintf = round-half-even
    int cy = (int)rintf(y * 64.0f);
    int cz = (int)rintf(z * 64.0f);
    cx = min(max(cx, 0), 64); cy = min(max(cy, 0), 64); cz = min(max(cz, 0), 64);
    pcoord[b * 4097 + 1 + p] = cx | (cy << 8) | (cz << 16);
  }
  if (tid == 0) pcoord[b * 4097] = 0;   // cls token coord (0,0,0)
}

// ---------------- voxel map ----------------
__global__ void init_idx(int* __restrict__ m) {
  int i = blockIdx.x * 256 + threadIdx.x;
  if (i < NVOX) m[i] = -1;
}

__global__ void scatter_idx(const int* __restrict__ pcoord, int* __restrict__ m) {
  int n = blockIdx.x * 256 + threadIdx.x;
  if (n >= NPTS) return;
  int c = pcoord[n];
  int lin = ((c & 255) * 65 + ((c >> 8) & 255)) * 65 + ((c >> 16) & 255);
  atomicMax(&m[lin], n);
}

// ---------------- neighbor ids: nid[k][n], invalid -> NPTS (zero row) ----------------
__global__ void nbr_kernel(const int* __restrict__ pcoord, const int* __restrict__ m,
                           int* __restrict__ nid) {
  int n = blockIdx.x * 256 + threadIdx.x;
  if (n >= MPAD) return;
  if (n >= NPTS) {
    for (int k = 0; k < 27; ++k) nid[k * MPAD + n] = NPTS;
    return;
  }
  int c = pcoord[n];
  int cx = c & 255, cy = (c >> 8) & 255, cz = (c >> 16) & 255;
#pragma unroll
  for (int k = 0; k < 27; ++k) {
    int nx = cx + k / 9 - 1;
    int ny = cy + (k / 3) % 3 - 1;
    int nz = cz + k % 3 - 1;
    int id = NPTS;
    if (((unsigned)nx <= 64u) && ((unsigned)ny <= 64u) && ((unsigned)nz <= 64u)) {
      int v = m[(nx * 65 + ny) * 65 + nz];
      if (v >= 0) id = v;
    }
    nid[k * MPAD + n] = id;
  }
}

// ---------------- features fp32 -> bf16 (+ zero row at NPTS) ----------------
__global__ void conv_feat(const float* __restrict__ f, u16* __restrict__ o) {
  int q = blockIdx.x * 256 + threadIdx.x;       // quad index
  if (q >= (NPTS + 1) * 64) return;
  us4 r;
  if (q < NPTS * 64) {
    float4 v = ((const float4*)f)[q];
    r.x = f2bf(v.x); r.y = f2bf(v.y); r.z = f2bf(v.z); r.w = f2bf(v.w);
  } else {
    r.x = 0; r.y = 0; r.z = 0; r.w = 0;
  }
  ((us4*)o)[q] = r;
}

// -------- weight fp32 [27][ci][co] -> bf16 wt2[step(216)][kchunk(4)][co(256)][8]
__global__ void conv_wt2(const float* __restrict__ w, u16* __restrict__ wt2) {
  int u = blockIdx.x * 256 + threadIdx.x;       // < 27*65536
  int e = u & 7, row = (u >> 3) & 255, lk = (u >> 11) & 3, ks = (u >> 13) & 7, ko = u >> 16;
  int ci = ks * 32 + lk * 8 + e;
  wt2[u] = f2bf(w[ko * 65536 + ci * 256 + row]);
}

// ---------------- gather-GEMM: out[N,256] = sum_k gather(feat, nid_k) @ W_k ----------------
__device__ __forceinline__ void gload16(const void* g, unsigned int lds_off) {
  __builtin_amdgcn_global_load_lds(
      (__attribute__((address_space(1))) void*)(size_t)g,
      (__attribute__((address_space(3))) void*)(unsigned int)lds_off,
      16, 0, 0);
}

// Block tile 128x256, 8 waves (2x4), wave tile 64x64, BK=32, mfma 16x16x32.
// A: gathered global->LDS (3-deep pipeline, XOR chunk swizzle).
// B: L2-resident weights loaded global->REGISTER (double-buffered 1 step ahead)
//    -> no B LDS traffic at all.
__global__ __launch_bounds__(512, 4) void gemm_kernel(const u16* __restrict__ feat,
                                                      const u16* __restrict__ wt,
                                                      const int* __restrict__ nid,
                                                      float* __restrict__ out) {
  __shared__ u16 As[3 * 4096];   // per buf 8KB: [row(128)][slot(4)][8e] (XOR-swizzled)
  int bm = blockIdx.x;
  int tid = threadIdx.x;
  int w = tid >> 6, l = tid & 63;
  int wr = w >> 2, wc = w & 3;     // wave tile (wr*64, wc*64)
  int lm = l & 15, lk = l >> 4;

  unsigned A0 = (unsigned)(size_t)&As[0];
  const char* Asc = (const char*)&As[0];

  const char* featc = (const char*)feat;
  const char* wtc = (const char*)wt;

  // A staging: 4 lanes per row (coalesced 64B), XOR chunk swizzle on source
  int row_l = (w << 4) + (l >> 2);
  int gmA = bm * 128 + row_l;
  int cA16 = (((l & 3) ^ ((row_l >> 1) & 3)) << 4);
  // B per-lane byte offset within a step tile: (lk*256 + wc*64 + lm) frag * 16B
  size_t bOff = (size_t)(((lk << 8) + (wc << 6) + lm) << 4);
  // A ds_read swizzle
  int aswz = lk ^ ((lm >> 1) & 3);

  f32x4 acc[4][4];
#pragma unroll
  for (int m = 0; m < 4; ++m)
#pragma unroll
    for (int n = 0; n < 4; ++n) acc[m][n] = (f32x4){0.f, 0.f, 0.f, 0.f};

  bf16x8 bcur[4], bnxt[4];

  int nv = nid[gmA];                // ko=0 gather row
  int nv_next = nv;

  // prologue: B(0) into regs; stage A(0), A(1) into bufs 0,1
  {
#pragma unroll
    for (int n = 0; n < 4; ++n)
      bcur[n] = *(const bf16x8*)(wtc + bOff + ((size_t)n << 8));
    gload16(featc + ((size_t)nv << 9) + cA16, A0 + (w << 10));
    gload16(featc + ((size_t)nv << 9) + 64 + cA16, A0 + 8192 + (w << 10));
  }

  unsigned a0 = 0, a1 = 8192, a2 = 16384;       // A buf byte offsets

  for (int ko = 0; ko < 27; ++ko) {
#pragma unroll
    for (int ks = 0; ks < 8; ++ks) {
      // ---- counted wait: ensure A(t) resident in LDS (see audit in notes) ----
      if (ko == 0 && ks == 0) {
        asm volatile("s_waitcnt vmcnt(1)" ::: "memory");
      } else if (ko == 26 && ks == 7) {
        asm volatile("s_waitcnt vmcnt(0)" ::: "memory");
      } else {
        asm volatile("s_waitcnt vmcnt(5)" ::: "memory");
      }
      __builtin_amdgcn_s_barrier();

      // ---- per-ko nid prefetch ----
      if (ks == 0 && ko < 26) nv_next = nid[(ko + 1) * MPAD + gmA];

      // ---- B(t+1) into bnxt (register prefetch; L2-resident) ----
      if (!(ko == 26 && ks == 7)) {
        const char* bp = wtc + ((size_t)(ko * 8 + ks + 1) << 14) + bOff;
#pragma unroll
        for (int n = 0; n < 4; ++n)
          bnxt[n] = *(const bf16x8*)(bp + ((size_t)n << 8));
      }

      // ---- stage A(t+2) into buf a2; stays in flight ~2 steps ----
      if (!(ko == 26 && ks >= 6)) {
        int snv = (ks >= 6) ? nv_next : nv;    // t+2 crosses into ko+1 iff ks>=6
        gload16(featc + ((size_t)snv << 9) + ((((ks) + 2) & 7) << 6) + cA16,
                A0 + a2 + (w << 10));
      }

      // ---- compute step t: A from LDS buf a0, B from bcur regs ----
      const bf16x8* Av = (const bf16x8*)(Asc + a0);
      bf16x8 afr[4];
#pragma unroll
      for (int m = 0; m < 4; ++m)
        afr[m] = Av[(((wr << 6) + (m << 4) + lm) << 2) + aswz];
      __builtin_amdgcn_s_setprio(1);
#pragma unroll
      for (int m = 0; m < 4; ++m)
#pragma unroll
        for (int n = 0; n < 4; ++n)
          acc[m][n] = __builtin_amdgcn_mfma_f32_16x16x32_bf16(afr[m], bcur[n],
                                                              acc[m][n], 0, 0, 0);
      __builtin_amdgcn_s_setprio(0);

      // ---- rename B buffers, rotate A bufs ----
#pragma unroll
      for (int n = 0; n < 4; ++n) bcur[n] = bnxt[n];
      { unsigned t_ = a0; a0 = a1; a1 = a2; a2 = t_; }
    }
    nv = nv_next;
  }

  // epilogue: D row = (lk*4+i), col = lm within each 16x16 frag
#pragma unroll
  for (int m = 0; m < 4; ++m) {
#pragma unroll
    for (int i = 0; i < 4; ++i) {
      int gr2 = bm * 128 + (wr << 6) + (m << 4) + (lk << 2) + i;
      if (gr2 < NPTS) {
        float* po = out + (size_t)gr2 * 256 + (wc << 6) + lm;
#pragma unroll
        for (int n = 0; n < 4; ++n) po[n << 4] = acc[m][n][i];
      }
    }
  }
}

extern "C" void kernel_launch(void* const* d_in, const int* in_sizes, int n_in,
                              void* d_out, int out_size, void* d_ws, size_t ws_size,
                              hipStream_t stream) {
  const float* features = (const float*)d_in[0];
  const float* depth = (const float*)d_in[1];
  const float* weight = (const float*)d_in[2];
  float* out = (float*)d_out;
  char* ws = (char*)d_ws;

  // ws layout (256B aligned)
  int* idx_map = (int*)(ws + 0);              // 274625 ints
  int* pcoord  = (int*)(ws + 1098752);        // 65552 ints
  int* nid     = (int*)(ws + 1361152);        // 27*65664 ints
  u16* feat_bf = (u16*)(ws + 8452864);        // (65552+1)*256 bf16
  u16* wt_bf   = (u16*)(ws + 42016256);       // 27*65536 bf16 (pre-arranged)
  // total ~45.6 MB

  coords_kernel<<<16, 256, 0, stream>>>(depth, pcoord);
  init_idx<<<(NVOX + 255) / 256, 256, 0, stream>>>(idx_map);
  scatter_idx<<<(NPTS + 255) / 256, 256, 0, stream>>>(pcoord, idx_map);
  nbr_kernel<<<(MPAD + 255) / 256, 256, 0, stream>>>(pcoord, idx_map, nid);
  conv_feat<<<((NPTS + 1) * 64 + 255) / 256, 256, 0, stream>>>(features, feat_bf);
  conv_wt2<<<27 * 65536 / 256, 256, 0, stream>>>(weight, wt_bf);
  gemm_kernel<<<513, 512, 0, stream>>>(feat_bf, wt_bf, nid, out);
}

// Round 11
// 325.611 us; speedup vs baseline: 1.0259x; 1.0259x over previous
//
#include <hip/hip_runtime.h>

#define NPTS 65552          // 16 * (64*64 + 1)
#define MPAD 65664          // 513 * 128
#define NVOX 274625         // 65^3

typedef unsigned short u16;
typedef __attribute__((ext_vector_type(8))) short bf16x8;
typedef __attribute__((ext_vector_type(4))) float f32x4;
typedef __attribute__((ext_vector_type(4))) unsigned short us4;

__device__ __forceinline__ u16 f2bf(float f) {
  unsigned int u = __float_as_uint(f);
  return (u16)((u + 0x7FFFu + ((u >> 16) & 1u)) >> 16);
}

// ---------------- coords from depth ----------------
__global__ void coords_kernel(const float* __restrict__ depth, int* __restrict__ pcoord) {
  int b = blockIdx.x, tid = threadIdx.x;
  const float* d = depth + b * 4096;
  float mn = 1e30f, mx = -1e30f;
  for (int p = tid; p < 4096; p += 256) {
    float v = d[p];
    mn = fminf(mn, v);
    mx = fmaxf(mx, v);
  }
  __shared__ float smn[256], smx[256];
  smn[tid] = mn; smx[tid] = mx;
  __syncthreads();
  for (int s = 128; s > 0; s >>= 1) {
    if (tid < s) {
      smn[tid] = fminf(smn[tid], smn[tid + s]);
      smx[tid] = fmaxf(smx[tid], smx[tid + s]);
    }
    __syncthreads();
  }
  mn = smn[0]; mx = smx[0];
  float den = mx - mn + 1e-8f;
  for (int p = tid; p < 4096; p += 256) {
    int i = p >> 6, j = p & 63;
    float x = (float)j / 63.0f;       // matches jnp arange/63 (IEEE div)
    float y = (float)i / 63.0f;
    float z = (d[p] - mn) / den;
    int cx = (int)rintf(x * 64.0f);   // *64 exact, rintf = round-half-even
    int cy = (int)rintf(y * 64.0f);
    int cz = (int)rintf(z * 64.0f);
    cx = min(max(cx, 0), 64); cy = min(max(cy, 0), 64); cz = min(max(cz, 0), 64);
    pcoord[b * 4097 + 1 + p] = cx | (cy << 8) | (cz << 16);
  }
  if (tid == 0) pcoord[b * 4097] = 0;   // cls token coord (0,0,0)
}

// ---------------- voxel map ----------------
__global__ void init_idx(int* __restrict__ m) {
  int i = blockIdx.x * 256 + threadIdx.x;
  if (i < NVOX) m[i] = -1;
}

__global__ void scatter_idx(const int* __restrict__ pcoord, int* __restrict__ m) {
  int n = blockIdx.x * 256 + threadIdx.x;
  if (n >= NPTS) return;
  int c = pcoord[n];
  int lin = ((c & 255) * 65 + ((c >> 8) & 255)) * 65 + ((c >> 16) & 255);
  atomicMax(&m[lin], n);
}

// ---------------- neighbor ids: nid[k][n], invalid -> NPTS (zero row) ----------------
__global__ void nbr_kernel(const int* __restrict__ pcoord, const int* __restrict__ m,
                           int* __restrict__ nid) {
  int n = blockIdx.x * 256 + threadIdx.x;
  if (n >= MPAD) return;
  if (n >= NPTS) {
    for (int k = 0; k < 27; ++k) nid[k * MPAD + n] = NPTS;
    return;
  }
  int c = pcoord[n];
  int cx = c & 255, cy = (c >> 8) & 255, cz = (c >> 16) & 255;
#pragma unroll
  for (int k = 0; k < 27; ++k) {
    int nx = cx + k / 9 - 1;
    int ny = cy + (k / 3) % 3 - 1;
    int nz = cz + k % 3 - 1;
    int id = NPTS;
    if (((unsigned)nx <= 64u) && ((unsigned)ny <= 64u) && ((unsigned)nz <= 64u)) {
      int v = m[(nx * 65 + ny) * 65 + nz];
      if (v >= 0) id = v;
    }
    nid[k * MPAD + n] = id;
  }
}

// ---------------- features fp32 -> bf16 (+ zero row at NPTS) ----------------
__global__ void conv_feat(const float* __restrict__ f, u16* __restrict__ o) {
  int q = blockIdx.x * 256 + threadIdx.x;       // quad index
  if (q >= (NPTS + 1) * 64) return;
  us4 r;
  if (q < NPTS * 64) {
    float4 v = ((const float4*)f)[q];
    r.x = f2bf(v.x); r.y = f2bf(v.y); r.z = f2bf(v.z); r.w = f2bf(v.w);
  } else {
    r.x = 0; r.y = 0; r.z = 0; r.w = 0;
  }
  ((us4*)o)[q] = r;
}

// -------- weight fp32 [27][ci][co] -> bf16 wt2[step(216)][kchunk(4)][co(256)][8]
__global__ void conv_wt2(const float* __restrict__ w, u16* __restrict__ wt2) {
  int u = blockIdx.x * 256 + threadIdx.x;       // < 27*65536
  int e = u & 7, row = (u >> 3) & 255, lk = (u >> 11) & 3, ks = (u >> 13) & 7, ko = u >> 16;
  int ci = ks * 32 + lk * 8 + e;
  wt2[u] = f2bf(w[ko * 65536 + ci * 256 + row]);
}

// ---------------- gather-GEMM: out[N,256] = sum_k gather(feat, nid_k) @ W_k ----------------
__device__ __forceinline__ void gload16(const void* g, unsigned int lds_off) {
  __builtin_amdgcn_global_load_lds(
      (__attribute__((address_space(1))) void*)(size_t)g,
      (__attribute__((address_space(3))) void*)(unsigned int)lds_off,
      16, 0, 0);
}

// Block tile 128x256, 8 waves (2x4), wave tile 64x64, BK=32, mfma 16x16x32.
// A: gathered global->LDS, 3-deep counted-vmcnt pipeline (R3 structure).
// B: L2-resident pre-arranged weights -> REGISTERS, ping-pong breg[2][4]
//    with compile-time parity (no rename copies) -> zero B LDS traffic.
__global__ __launch_bounds__(512, 4) void gemm_kernel(const u16* __restrict__ feat,
                                                      const u16* __restrict__ wt,
                                                      const int* __restrict__ nid,
                                                      float* __restrict__ out) {
  __shared__ u16 As[3 * 4096];   // per buf 8KB: [row(128)][slot(4)][8e] (XOR-swizzled)
  int bm = blockIdx.x;
  int tid = threadIdx.x;
  int w = tid >> 6, l = tid & 63;
  int wr = w >> 2, wc = w & 3;     // wave tile (wr*64, wc*64)
  int lm = l & 15, lk = l >> 4;

  unsigned A0 = (unsigned)(size_t)&As[0];
  const char* Asc = (const char*)&As[0];

  const char* featc = (const char*)feat;
  const char* wtc = (const char*)wt;

  // A staging: 4 lanes per row (coalesced 64B), XOR chunk swizzle on source
  int row_l = (w << 4) + (l >> 2);
  int gmA = bm * 128 + row_l;
  int cA16 = (((l & 3) ^ ((row_l >> 1) & 3)) << 4);
  // B per-lane byte offset within a 16KB step tile
  size_t bOff = (size_t)(((lk << 8) + (wc << 6) + lm) << 4);
  // A ds_read swizzle
  int aswz = lk ^ ((lm >> 1) & 3);

  f32x4 acc[4][4];
#pragma unroll
  for (int m = 0; m < 4; ++m)
#pragma unroll
    for (int n = 0; n < 4; ++n) acc[m][n] = (f32x4){0.f, 0.f, 0.f, 0.f};

  bf16x8 breg[2][4];               // ping-pong; step t uses breg[t&1]

  int nv = nid[gmA];                // ko=0 gather row
  int nv_next = nv;

  // prologue: B(0) regs; stage A(0), A(1) into bufs 0,1
  {
#pragma unroll
    for (int n = 0; n < 4; ++n)
      breg[0][n] = *(const bf16x8*)(wtc + bOff + ((size_t)n << 8));
    gload16(featc + ((size_t)nv << 9) + cA16, A0 + (w << 10));
    gload16(featc + ((size_t)nv << 9) + 64 + cA16, A0 + 8192 + (w << 10));
  }

  const char* bp = wtc + 16384 + bOff;          // source for B(t+1), advances 16KB/step

  unsigned a0 = 0, a1 = 8192, a2 = 16384;       // A buf byte offsets

  for (int ko = 0; ko < 27; ++ko) {
#pragma unroll
    for (int ks = 0; ks < 8; ++ks) {
      // ---- counted wait: retire A(t); keep newer loads in flight ----
      if (ko == 0 && ks == 0) {
        asm volatile("s_waitcnt vmcnt(1)" ::: "memory");
      } else if (ko == 26 && ks == 7) {
        asm volatile("s_waitcnt vmcnt(0)" ::: "memory");
      } else if (ks == 1 && ko < 26) {
        asm volatile("s_waitcnt vmcnt(6)" ::: "memory");   // +1 boundary nid load
      } else {
        asm volatile("s_waitcnt vmcnt(5)" ::: "memory");
      }
      __builtin_amdgcn_s_barrier();

      // ---- per-ko nid prefetch ----
      if (ks == 0 && ko < 26) nv_next = nid[(ko + 1) * MPAD + gmA];

      // ---- B(t+1) into breg[(ks+1)&1] (L2-resident; consumed next step) ----
      if (!(ko == 26 && ks == 7)) {
#pragma unroll
        for (int n = 0; n < 4; ++n)
          breg[(ks + 1) & 1][n] = *(const bf16x8*)(bp + ((size_t)n << 8));
        bp += 16384;
      }

      // ---- stage A(t+2) into buf a2; stays in flight ~2 steps ----
      if (!(ko == 26 && ks >= 6)) {
        int snv = (ks >= 6) ? nv_next : nv;    // t+2 crosses into ko+1 iff ks>=6
        gload16(featc + ((size_t)snv << 9) + (((ks + 2) & 7) << 6) + cA16,
                A0 + a2 + (w << 10));
      }

      // ---- compute step t: A from LDS buf a0, B from breg[ks&1] ----
      const bf16x8* Av = (const bf16x8*)(Asc + a0);
      bf16x8 afr[4];
#pragma unroll
      for (int m = 0; m < 4; ++m)
        afr[m] = Av[(((wr << 6) + (m << 4) + lm) << 2) + aswz];
      __builtin_amdgcn_s_setprio(1);
#pragma unroll
      for (int m = 0; m < 4; ++m)
#pragma unroll
        for (int n = 0; n < 4; ++n)
          acc[m][n] = __builtin_amdgcn_mfma_f32_16x16x32_bf16(afr[m], breg[ks & 1][n],
                                                              acc[m][n], 0, 0, 0);
      __builtin_amdgcn_s_setprio(0);

      // ---- rotate A bufs ----
      { unsigned t_ = a0; a0 = a1; a1 = a2; a2 = t_; }
    }
    nv = nv_next;
  }

  // epilogue: D row = (lk*4+i), col = lm within each 16x16 frag
#pragma unroll
  for (int m = 0; m < 4; ++m) {
#pragma unroll
    for (int i = 0; i < 4; ++i) {
      int gr2 = bm * 128 + (wr << 6) + (m << 4) + (lk << 2) + i;
      if (gr2 < NPTS) {
        float* po = out + (size_t)gr2 * 256 + (wc << 6) + lm;
#pragma unroll
        for (int n = 0; n < 4; ++n) po[n << 4] = acc[m][n][i];
      }
    }
  }
}

extern "C" void kernel_launch(void* const* d_in, const int* in_sizes, int n_in,
                              void* d_out, int out_size, void* d_ws, size_t ws_size,
                              hipStream_t stream) {
  const float* features = (const float*)d_in[0];
  const float* depth = (const float*)d_in[1];
  const float* weight = (const float*)d_in[2];
  float* out = (float*)d_out;
  char* ws = (char*)d_ws;

  // ws layout (256B aligned)
  int* idx_map = (int*)(ws + 0);              // 274625 ints
  int* pcoord  = (int*)(ws + 1098752);        // 65552 ints
  int* nid     = (int*)(ws + 1361152);        // 27*65664 ints
  u16* feat_bf = (u16*)(ws + 8452864);        // (65552+1)*256 bf16
  u16* wt_bf   = (u16*)(ws + 42016256);       // 27*65536 bf16 (pre-arranged)
  // total ~45.6 MB

  coords_kernel<<<16, 256, 0, stream>>>(depth, pcoord);
  init_idx<<<(NVOX + 255) / 256, 256, 0, stream>>>(idx_map);
  scatter_idx<<<(NPTS + 255) / 256, 256, 0, stream>>>(pcoord, idx_map);
  nbr_kernel<<<(MPAD + 255) / 256, 256, 0, stream>>>(pcoord, idx_map, nid);
  conv_feat<<<((NPTS + 1) * 64 + 255) / 256, 256, 0, stream>>>(features, feat_bf);
  conv_wt2<<<27 * 65536 / 256, 256, 0, stream>>>(weight, wt_bf);
  gemm_kernel<<<513, 512, 0, stream>>>(feat_bf, wt_bf, nid, out);
}

// Round 12
// 263.626 us; speedup vs baseline: 1.2671x; 1.2351x over previous
//
#include <hip/hip_runtime.h>

#define NPTS 65552          // 16 * (64*64 + 1)
#define MPAD 65664          // 1026 * 64
#define NVOX 274625         // 65^3

typedef unsigned short u16;
typedef __attribute__((ext_vector_type(8))) short bf16x8;
typedef __attribute__((ext_vector_type(4))) float f32x4;
typedef __attribute__((ext_vector_type(4))) unsigned short us4;

__device__ __forceinline__ u16 f2bf(float f) {
  unsigned int u = __float_as_uint(f);
  return (u16)((u + 0x7FFFu + ((u >> 16) & 1u)) >> 16);
}

// ---------------- coords from depth ----------------
__global__ void coords_kernel(const float* __restrict__ depth, int* __restrict__ pcoord) {
  int b = blockIdx.x, tid = threadIdx.x;
  const float* d = depth + b * 4096;
  float mn = 1e30f, mx = -1e30f;
  for (int p = tid; p < 4096; p += 256) {
    float v = d[p];
    mn = fminf(mn, v);
    mx = fmaxf(mx, v);
  }
  __shared__ float smn[256], smx[256];
  smn[tid] = mn; smx[tid] = mx;
  __syncthreads();
  for (int s = 128; s > 0; s >>= 1) {
    if (tid < s) {
      smn[tid] = fminf(smn[tid], smn[tid + s]);
      smx[tid] = fmaxf(smx[tid], smx[tid + s]);
    }
    __syncthreads();
  }
  mn = smn[0]; mx = smx[0];
  float den = mx - mn + 1e-8f;
  for (int p = tid; p < 4096; p += 256) {
    int i = p >> 6, j = p & 63;
    float x = (float)j / 63.0f;       // matches jnp arange/63 (IEEE div)
    float y = (float)i / 63.0f;
    float z = (d[p] - mn) / den;
    int cx = (int)rintf(x * 64.0f);   // *64 exact, rintf = round-half-even
    int cy = (int)rintf(y * 64.0f);
    int cz = (int)rintf(z * 64.0f);
    cx = min(max(cx, 0), 64); cy = min(max(cy, 0), 64); cz = min(max(cz, 0), 64);
    pcoord[b * 4097 + 1 + p] = cx | (cy << 8) | (cz << 16);
  }
  if (tid == 0) pcoord[b * 4097] = 0;   // cls token coord (0,0,0)
}

// ---------------- voxel map ----------------
__global__ void init_idx(int* __restrict__ m) {
  int i = blockIdx.x * 256 + threadIdx.x;
  if (i < NVOX) m[i] = -1;
}

__global__ void scatter_idx(const int* __restrict__ pcoord, int* __restrict__ m) {
  int n = blockIdx.x * 256 + threadIdx.x;
  if (n >= NPTS) return;
  int c = pcoord[n];
  int lin = ((c & 255) * 65 + ((c >> 8) & 255)) * 65 + ((c >> 16) & 255);
  atomicMax(&m[lin], n);
}

// ---------------- neighbor ids: nid[k][n], invalid -> NPTS (zero row) ----------------
__global__ void nbr_kernel(const int* __restrict__ pcoord, const int* __restrict__ m,
                           int* __restrict__ nid) {
  int n = blockIdx.x * 256 + threadIdx.x;
  if (n >= MPAD) return;
  if (n >= NPTS) {
    for (int k = 0; k < 27; ++k) nid[k * MPAD + n] = NPTS;
    return;
  }
  int c = pcoord[n];
  int cx = c & 255, cy = (c >> 8) & 255, cz = (c >> 16) & 255;
#pragma unroll
  for (int k = 0; k < 27; ++k) {
    int nx = cx + k / 9 - 1;
    int ny = cy + (k / 3) % 3 - 1;
    int nz = cz + k % 3 - 1;
    int id = NPTS;
    if (((unsigned)nx <= 64u) && ((unsigned)ny <= 64u) && ((unsigned)nz <= 64u)) {
      int v = m[(nx * 65 + ny) * 65 + nz];
      if (v >= 0) id = v;
    }
    nid[k * MPAD + n] = id;
  }
}

// ---------------- features fp32 -> bf16 (+ zero row at NPTS) ----------------
__global__ void conv_feat(const float* __restrict__ f, u16* __restrict__ o) {
  int q = blockIdx.x * 256 + threadIdx.x;       // quad index
  if (q >= (NPTS + 1) * 64) return;
  us4 r;
  if (q < NPTS * 64) {
    float4 v = ((const float4*)f)[q];
    r.x = f2bf(v.x); r.y = f2bf(v.y); r.z = f2bf(v.z); r.w = f2bf(v.w);
  } else {
    r.x = 0; r.y = 0; r.z = 0; r.w = 0;
  }
  ((us4*)o)[q] = r;
}

// -------- weight fp32 [27][ci][co] -> bf16 wt2[step(216)][kchunk(4)][co(256)][8]
__global__ void conv_wt2(const float* __restrict__ w, u16* __restrict__ wt2) {
  int u = blockIdx.x * 256 + threadIdx.x;       // < 27*65536
  int e = u & 7, row = (u >> 3) & 255, lk = (u >> 11) & 3, ks = (u >> 13) & 7, ko = u >> 16;
  int ci = ks * 32 + lk * 8 + e;
  wt2[u] = f2bf(w[ko * 65536 + ci * 256 + row]);
}

// ---------------- gather-GEMM: out[N,256] = sum_k gather(feat, nid_k) @ W_k ----------------
__device__ __forceinline__ void gload16(const void* g, unsigned int lds_off) {
  __builtin_amdgcn_global_load_lds(
      (__attribute__((address_space(1))) void*)(size_t)g,
      (__attribute__((address_space(3))) void*)(unsigned int)lds_off,
      16, 0, 0);
}

// Block tile 64x256, 4 waves (1x4), wave tile 64x64, BK=32, mfma 16x16x32.
// A: gathered global->LDS, 3-deep counted-vmcnt pipeline (R3 structure, 4KB bufs).
// B: L2-resident pre-arranged weights -> REGISTERS ping-pong (zero B LDS traffic).
// 256-thr blocks + launch_bounds(256,3): ~168-reg budget -> acc(64)+breg(32)+afr(16)
// fit WITHOUT spill at 3 blocks/CU (12 waves/CU).
__global__ __launch_bounds__(256, 3) void gemm_kernel(const u16* __restrict__ feat,
                                                      const u16* __restrict__ wt,
                                                      const int* __restrict__ nid,
                                                      float* __restrict__ out) {
  __shared__ u16 As[3 * 2048];   // per buf 4KB: [row(64)][slot(4)][8e] (XOR-swizzled)
  int bm = blockIdx.x;
  int tid = threadIdx.x;
  int w = tid >> 6, l = tid & 63;  // 4 waves; wave w owns cols w*64..w*64+63
  int lm = l & 15, lk = l >> 4;

  unsigned A0 = (unsigned)(size_t)&As[0];
  const char* Asc = (const char*)&As[0];

  const char* featc = (const char*)feat;
  const char* wtc = (const char*)wt;

  // A staging: wave w stages rows w*16..w*16+15 (1 gload16 = 1KB; 4 lanes/row,
  // 16B/lane, coalesced 64B/row). XOR chunk swizzle on the global source.
  int row_l = (w << 4) + (l >> 2);
  int gmA = bm * 64 + row_l;
  int cA16 = (((l & 3) ^ ((row_l >> 1) & 3)) << 4);
  // B per-lane byte offset within a 16KB step tile: (lk*256 + w*64 + lm) * 16B
  size_t bOff = (size_t)(((lk << 8) + (w << 6) + lm) << 4);
  // A ds_read swizzle: slot = lk ^ ((row>>1)&3); row dep reduces to lm bits
  int aswz = lk ^ ((lm >> 1) & 3);

  f32x4 acc[4][4];
#pragma unroll
  for (int m = 0; m < 4; ++m)
#pragma unroll
    for (int n = 0; n < 4; ++n) acc[m][n] = (f32x4){0.f, 0.f, 0.f, 0.f};

  bf16x8 breg[2][4];               // ping-pong; step t uses breg[t&1]

  int nv = nid[gmA];                // ko=0 gather row
  int nv_next = nv;

  // prologue: B(0) into regs; stage A(0), A(1) into bufs 0,1
  {
#pragma unroll
    for (int n = 0; n < 4; ++n)
      breg[0][n] = *(const bf16x8*)(wtc + bOff + ((size_t)n << 8));
    gload16(featc + ((size_t)nv << 9) + cA16, A0 + (w << 10));
    gload16(featc + ((size_t)nv << 9) + 64 + cA16, A0 + 4096 + (w << 10));
  }

  const char* bp = wtc + 16384 + bOff;          // B(t+1) source, advances 16KB/step

  unsigned a0 = 0, a1 = 4096, a2 = 8192;        // A buf byte offsets

  for (int ko = 0; ko < 27; ++ko) {
#pragma unroll
    for (int ks = 0; ks < 8; ++ks) {
      // ---- counted wait: retire A(t); keep newer loads in flight ----
      if (ko == 0 && ks == 0) {
        asm volatile("s_waitcnt vmcnt(1)" ::: "memory");
      } else if (ko == 26 && ks == 7) {
        asm volatile("s_waitcnt vmcnt(0)" ::: "memory");
      } else if (ks == 1 && ko < 26) {
        asm volatile("s_waitcnt vmcnt(6)" ::: "memory");   // +1 boundary nid load
      } else {
        asm volatile("s_waitcnt vmcnt(5)" ::: "memory");
      }
      __builtin_amdgcn_s_barrier();

      // ---- per-ko nid prefetch ----
      if (ks == 0 && ko < 26) nv_next = nid[(ko + 1) * MPAD + gmA];

      // ---- B(t+1) into breg[(ks+1)&1] (L2-resident; consumed next step) ----
      if (!(ko == 26 && ks == 7)) {
#pragma unroll
        for (int n = 0; n < 4; ++n)
          breg[(ks + 1) & 1][n] = *(const bf16x8*)(bp + ((size_t)n << 8));
        bp += 16384;
      }

      // ---- stage A(t+2) into buf a2; stays in flight ~2 steps ----
      if (!(ko == 26 && ks >= 6)) {
        int snv = (ks >= 6) ? nv_next : nv;    // t+2 crosses into ko+1 iff ks>=6
        gload16(featc + ((size_t)snv << 9) + (((ks + 2) & 7) << 6) + cA16,
                A0 + a2 + (w << 10));
      }

      // ---- compute step t: A from LDS buf a0, B from breg[ks&1] ----
      const bf16x8* Av = (const bf16x8*)(Asc + a0);
      bf16x8 afr[4];
#pragma unroll
      for (int m = 0; m < 4; ++m)
        afr[m] = Av[(((m << 4) + lm) << 2) + aswz];
      __builtin_amdgcn_s_setprio(1);
#pragma unroll
      for (int m = 0; m < 4; ++m)
#pragma unroll
        for (int n = 0; n < 4; ++n)
          acc[m][n] = __builtin_amdgcn_mfma_f32_16x16x32_bf16(afr[m], breg[ks & 1][n],
                                                              acc[m][n], 0, 0, 0);
      __builtin_amdgcn_s_setprio(0);

      // ---- rotate A bufs ----
      { unsigned t_ = a0; a0 = a1; a1 = a2; a2 = t_; }
    }
    nv = nv_next;
  }

  // epilogue: D row = m*16 + lk*4 + i, col = w*64 + n*16 + lm
#pragma unroll
  for (int m = 0; m < 4; ++m) {
#pragma unroll
    for (int i = 0; i < 4; ++i) {
      int gr2 = bm * 64 + (m << 4) + (lk << 2) + i;
      if (gr2 < NPTS) {
        float* po = out + (size_t)gr2 * 256 + (w << 6) + lm;
#pragma unroll
        for (int n = 0; n < 4; ++n) po[n << 4] = acc[m][n][i];
      }
    }
  }
}

extern "C" void kernel_launch(void* const* d_in, const int* in_sizes, int n_in,
                              void* d_out, int out_size, void* d_ws, size_t ws_size,
                              hipStream_t stream) {
  const float* features = (const float*)d_in[0];
  const float* depth = (const float*)d_in[1];
  const float* weight = (const float*)d_in[2];
  float* out = (float*)d_out;
  char* ws = (char*)d_ws;

  // ws layout (256B aligned)
  int* idx_map = (int*)(ws + 0);              // 274625 ints
  int* pcoord  = (int*)(ws + 1098752);        // 65552 ints
  int* nid     = (int*)(ws + 1361152);        // 27*65664 ints
  u16* feat_bf = (u16*)(ws + 8452864);        // (65552+1)*256 bf16
  u16* wt_bf   = (u16*)(ws + 42016256);       // 27*65536 bf16 (pre-arranged)
  // total ~45.6 MB

  coords_kernel<<<16, 256, 0, stream>>>(depth, pcoord);
  init_idx<<<(NVOX + 255) / 256, 256, 0, stream>>>(idx_map);
  scatter_idx<<<(NPTS + 255) / 256, 256, 0, stream>>>(pcoord, idx_map);
  nbr_kernel<<<(MPAD + 255) / 256, 256, 0, stream>>>(pcoord, idx_map, nid);
  conv_feat<<<((NPTS + 1) * 64 + 255) / 256, 256, 0, stream>>>(features, feat_bf);
  conv_wt2<<<27 * 65536 / 256, 256, 0, stream>>>(weight, wt_bf);
  gemm_kernel<<<1026, 256, 0, stream>>>(feat_bf, wt_bf, nid, out);
}